// Round 1
// baseline (1050.358 us; speedup 1.0000x reference)
//
#include <hip/hip_runtime.h>
#include <math.h>

// GraphSage GNN forward, fp32. N=100000 (div by 32), E=600000, HID=128, OUT=40, G=64, L=3.

static inline size_t alignup(size_t x){ return (x + 255) & ~(size_t)255; }

// ---------------- CSR build ----------------
__global__ void count_kernel(const int* __restrict__ ei, int E, int* __restrict__ cnt){
  int e = blockIdx.x*256 + threadIdx.x;
  if (e < E) atomicAdd(&cnt[ei[E + e]], 1);   // dst row
}

__global__ void scan1_kernel(const int* __restrict__ cnt, int* __restrict__ rs,
                             int* __restrict__ bsum, int N){
  __shared__ int s[256];
  int t = threadIdx.x;
  int i = blockIdx.x*256 + t;
  int v = (i < N) ? cnt[i] : 0;
  s[t] = v; __syncthreads();
  for (int off = 1; off < 256; off <<= 1){
    int x = (t >= off) ? s[t-off] : 0;
    __syncthreads();
    s[t] += x;
    __syncthreads();
  }
  if (i < N) rs[i] = s[t] - v;          // block-local exclusive
  if (t == 255) bsum[blockIdx.x] = s[255];
}

__global__ void scan2_kernel(int* __restrict__ bsum, int NB){
  __shared__ int s[512];
  int t = threadIdx.x;
  int v = (t < NB) ? bsum[t] : 0;
  s[t] = v; __syncthreads();
  for (int off = 1; off < 512; off <<= 1){
    int x = (t >= off) ? s[t-off] : 0;
    __syncthreads();
    s[t] += x;
    __syncthreads();
  }
  if (t < NB) bsum[t] = s[t] - v;       // exclusive over block sums
}

__global__ void scan3_kernel(int* __restrict__ rs, const int* __restrict__ bsum,
                             int* __restrict__ cur, int N){
  int i = blockIdx.x*256 + threadIdx.x;
  if (i < N){
    int v = rs[i] + bsum[blockIdx.x];
    rs[i] = v;
    cur[i] = v;
  }
}

__global__ void fill_kernel(const int* __restrict__ ei, int E, int* __restrict__ cur,
                            int* __restrict__ esrc){
  int e = blockIdx.x*256 + threadIdx.x;
  if (e < E){
    int d = ei[E + e];
    int p = atomicAdd(&cur[d], 1);
    esrc[p] = ei[e];                    // src node id
  }
}

// ---------------- collapsed postMP weights: Wc = W2@W1 (40x128), bc = W2@b1 + b2 ----------------
__global__ void wc_kernel(const float* __restrict__ W1, const float* __restrict__ b1,
                          const float* __restrict__ W2, const float* __restrict__ b2,
                          float* __restrict__ Wc, float* __restrict__ bc){
  int o = blockIdx.x;        // 0..39
  int k = threadIdx.x;       // 0..127
  float s = 0.0f;
  for (int j = 0; j < 128; ++j) s = fmaf(W2[o*128 + j], W1[j*128 + k], s);
  Wc[o*128 + k] = s;
  __shared__ float r[128];
  r[k] = W2[o*128 + k] * b1[k];
  __syncthreads();
  for (int off = 64; off; off >>= 1){
    if (k < off) r[k] += r[k + off];
    __syncthreads();
  }
  if (k == 0) bc[o] = r[0] + b2[o];
}

// ---------------- dual GEMM: Ca = act(A)@Wa^T + ba (cols 0..127), Cb = act(A)@Wb^T + bb (128..255)
// act(v) = use_act ? relu(v*scale + shift) : v, with bnp = {scale[128], shift[128]} (prev layer BN)
__global__ __launch_bounds__(512, 1) void gemm_dual(
    const float* __restrict__ A, const float* __restrict__ bnp, int use_act,
    const float* __restrict__ Wa, const float* __restrict__ ba,
    const float* __restrict__ Wb, const float* __restrict__ bb,
    float* __restrict__ Ca, float* __restrict__ Cb, int N)
{
  __shared__ float wlds[128*256];   // [k][c], 128 KB
  __shared__ float alds[128*36];    // [k][row], pad 36 keeps 16B align + spreads banks, 18 KB
  const int t = threadIdx.x;

  // Stage W: lanes take consecutive c (conflict-free LDS writes); global reads are 16B gathers (L2, one-time)
  for (int q = t; q < 256*32; q += 512){
    int c = q & 255, kq = q >> 8;
    const float* wsrc = (c < 128) ? (Wa + c*128) : (Wb + (c-128)*128);
    float4 v = *(const float4*)(wsrc + kq*4);
    wlds[(kq*4+0)*256 + c] = v.x;
    wlds[(kq*4+1)*256 + c] = v.y;
    wlds[(kq*4+2)*256 + c] = v.z;
    wlds[(kq*4+3)*256 + c] = v.w;
  }
  const int tx = t & 63;   // cols tx*4 .. tx*4+3
  const int ty = t >> 6;   // rows ty*4 .. ty*4+3
  float bias[4];
  #pragma unroll
  for (int j = 0; j < 4; ++j){
    int c = tx*4 + j;
    bias[j] = (c < 128) ? ba[c] : bb[c - 128];
  }
  const int ntiles = N >> 5;   // N % 32 == 0
  for (int tile = blockIdx.x; tile < ntiles; tile += gridDim.x){
    const int rbase = tile << 5;
    __syncthreads();   // alds reuse + W-stage fence on first iter
    for (int q = t; q < 32*32; q += 512){
      int row = q >> 5, kq = q & 31;
      float4 v = *(const float4*)(A + (size_t)(rbase + row)*128 + kq*4);
      if (use_act){
        float4 sc = *(const float4*)(bnp + kq*4);
        float4 sh = *(const float4*)(bnp + 128 + kq*4);
        v.x = fmaxf(fmaf(v.x, sc.x, sh.x), 0.0f);
        v.y = fmaxf(fmaf(v.y, sc.y, sh.y), 0.0f);
        v.z = fmaxf(fmaf(v.z, sc.z, sh.z), 0.0f);
        v.w = fmaxf(fmaf(v.w, sc.w, sh.w), 0.0f);
      }
      alds[(kq*4+0)*36 + row] = v.x;
      alds[(kq*4+1)*36 + row] = v.y;
      alds[(kq*4+2)*36 + row] = v.z;
      alds[(kq*4+3)*36 + row] = v.w;
    }
    __syncthreads();
    float acc[4][4];
    #pragma unroll
    for (int i = 0; i < 4; ++i)
      #pragma unroll
      for (int j = 0; j < 4; ++j) acc[i][j] = bias[j];
    #pragma unroll 4
    for (int k = 0; k < 128; ++k){
      float4 av = *(const float4*)(alds + k*36 + ty*4);   // broadcast across tx
      float4 wv = *(const float4*)(wlds + k*256 + tx*4);  // contiguous across lanes
      float avv[4] = {av.x, av.y, av.z, av.w};
      float wvv[4] = {wv.x, wv.y, wv.z, wv.w};
      #pragma unroll
      for (int i = 0; i < 4; ++i)
        #pragma unroll
        for (int j = 0; j < 4; ++j)
          acc[i][j] = fmaf(avv[i], wvv[j], acc[i][j]);
    }
    const int cbase = tx*4;
    #pragma unroll
    for (int i = 0; i < 4; ++i){
      int row = rbase + ty*4 + i;
      float4 o = make_float4(acc[i][0], acc[i][1], acc[i][2], acc[i][3]);
      if (cbase < 128) *(float4*)(Ca + (size_t)row*128 + cbase) = o;
      else             *(float4*)(Cb + (size_t)row*128 + (cbase - 128)) = o;
    }
  }
}

// ---------------- z GEMM: Z = act(A)@Wc^T + bc (N x 40), cols padded to 64 ----------------
__global__ __launch_bounds__(512, 1) void gemm_z(
    const float* __restrict__ A, const float* __restrict__ bnp,
    const float* __restrict__ Wc, const float* __restrict__ bc,
    float* __restrict__ Z, int N)
{
  __shared__ float wlds[128*64];
  __shared__ float alds[128*36];
  const int t = threadIdx.x;
  for (int q = t; q < 64*32; q += 512){
    int c = q & 63, kq = q >> 6;
    float4 v = make_float4(0.f, 0.f, 0.f, 0.f);
    if (c < 40) v = *(const float4*)(Wc + c*128 + kq*4);
    wlds[(kq*4+0)*64 + c] = v.x;
    wlds[(kq*4+1)*64 + c] = v.y;
    wlds[(kq*4+2)*64 + c] = v.z;
    wlds[(kq*4+3)*64 + c] = v.w;
  }
  const int tx = t & 63;   // one col per thread
  const int ty = t >> 6;   // rows ty*4..+3
  float bias = (tx < 40) ? bc[tx] : 0.0f;
  const int ntiles = N >> 5;
  for (int tile = blockIdx.x; tile < ntiles; tile += gridDim.x){
    const int rbase = tile << 5;
    __syncthreads();
    for (int q = t; q < 32*32; q += 512){
      int row = q >> 5, kq = q & 31;
      float4 v = *(const float4*)(A + (size_t)(rbase + row)*128 + kq*4);
      float4 sc = *(const float4*)(bnp + kq*4);
      float4 sh = *(const float4*)(bnp + 128 + kq*4);
      v.x = fmaxf(fmaf(v.x, sc.x, sh.x), 0.0f);
      v.y = fmaxf(fmaf(v.y, sc.y, sh.y), 0.0f);
      v.z = fmaxf(fmaf(v.z, sc.z, sh.z), 0.0f);
      v.w = fmaxf(fmaf(v.w, sc.w, sh.w), 0.0f);
      alds[(kq*4+0)*36 + row] = v.x;
      alds[(kq*4+1)*36 + row] = v.y;
      alds[(kq*4+2)*36 + row] = v.z;
      alds[(kq*4+3)*36 + row] = v.w;
    }
    __syncthreads();
    float acc[4] = {bias, bias, bias, bias};
    #pragma unroll 4
    for (int k = 0; k < 128; ++k){
      float4 av = *(const float4*)(alds + k*36 + ty*4);
      float w = wlds[k*64 + tx];
      acc[0] = fmaf(av.x, w, acc[0]);
      acc[1] = fmaf(av.y, w, acc[1]);
      acc[2] = fmaf(av.z, w, acc[2]);
      acc[3] = fmaf(av.w, w, acc[3]);
    }
    if (tx < 40){
      #pragma unroll
      for (int i = 0; i < 4; ++i)
        Z[(size_t)(rbase + ty*4 + i)*40 + tx] = acc[i];
    }
  }
}

// ---------------- aggregation: h2 = hWl + gather-mean(m) ; L2-normalize ; accumulate BN stats
__global__ void agg_kernel(const float* __restrict__ m, const int* __restrict__ rs,
                           const int* __restrict__ cnt, const int* __restrict__ esrc,
                           float* __restrict__ h, float* __restrict__ colstats, int N)
{
  __shared__ float redS[4][128];
  __shared__ float redQ[4][128];
  const int t = threadIdx.x;
  const int w = t >> 6, lane = t & 63;
  float s0 = 0.f, s1 = 0.f, q0 = 0.f, q1 = 0.f;
  for (int n = blockIdx.x*4 + w; n < N; n += gridDim.x*4){
    int start = rs[n];
    int c = cnt[n];
    float ax = 0.f, ay = 0.f;
    for (int e = 0; e < c; ++e){
      int src = esrc[start + e];
      float2 v = *(const float2*)(m + (size_t)src*128 + lane*2);
      ax += v.x; ay += v.y;
    }
    float inv = 1.0f / (float)max(c, 1);
    float2 hv = *(float2*)(h + (size_t)n*128 + lane*2);
    float x = fmaf(ax, inv, hv.x);
    float y = fmaf(ay, inv, hv.y);
    float ss = x*x + y*y;
    #pragma unroll
    for (int off = 32; off; off >>= 1) ss += __shfl_xor(ss, off);
    float scale = 1.0f / fmaxf(sqrtf(ss), 1e-12f);
    x *= scale; y *= scale;
    *(float2*)(h + (size_t)n*128 + lane*2) = make_float2(x, y);
    s0 += x; s1 += y; q0 += x*x; q1 += y*y;
  }
  redS[w][lane*2]   = s0; redS[w][lane*2+1] = s1;
  redQ[w][lane*2]   = q0; redQ[w][lane*2+1] = q1;
  __syncthreads();
  if (t < 128){
    float S = redS[0][t] + redS[1][t] + redS[2][t] + redS[3][t];
    float Q = redQ[0][t] + redQ[1][t] + redQ[2][t] + redQ[3][t];
    atomicAdd(&colstats[t], S);
    atomicAdd(&colstats[128 + t], Q);
  }
}

// ---------------- BN params: scale/shift for the *next* kernel's fused act; zero stats for next layer
__global__ void bn_params_kernel(float* __restrict__ cs, const float* __restrict__ gamma,
                                 const float* __restrict__ beta, float* __restrict__ bnp, float Nf){
  int t = threadIdx.x;   // 0..127
  float sum = cs[t], sq = cs[128 + t];
  float mu  = sum / Nf;
  float var = fmaxf(sq / Nf - mu*mu, 0.0f);
  float inv = rsqrtf(var + 1e-5f);
  float scale = gamma[t] * inv;
  bnp[t] = scale;
  bnp[128 + t] = beta[t] - mu * scale;
  cs[t] = 0.0f; cs[128 + t] = 0.0f;
}

// ---------------- pooled log-softmax, one block per graph (batch is sorted) ----------------
__global__ void pool_lsm_kernel(const float* __restrict__ z, const int* __restrict__ batch,
                                int N, float* __restrict__ out)
{
  __shared__ int lohi[2];
  __shared__ float part[6][40];
  __shared__ float prow[40];
  const int g = blockIdx.x;
  const int t = threadIdx.x;
  if (t == 0){
    int lo = 0, hi = N;
    while (lo < hi){ int mid = (lo + hi) >> 1; if (batch[mid] < g) lo = mid + 1; else hi = mid; }
    lohi[0] = lo;
    int lo2 = lo, hi2 = N;
    while (lo2 < hi2){ int mid = (lo2 + hi2) >> 1; if (batch[mid] < g + 1) lo2 = mid + 1; else hi2 = mid; }
    lohi[1] = lo2;
  }
  __syncthreads();
  const int lo = lohi[0], hi = lohi[1];
  if (t < 240){
    int c = t % 40, nl = t / 40;
    float acc = 0.f;
    for (int n = lo + nl; n < hi; n += 6) acc += z[(size_t)n*40 + c];
    part[nl][c] = acc;
  }
  __syncthreads();
  if (t < 40) prow[t] = part[0][t] + part[1][t] + part[2][t] + part[3][t] + part[4][t] + part[5][t];
  __syncthreads();
  if (t < 64){
    float v = (t < 40) ? prow[t] : -3.0e38f;
    float mx = v;
    #pragma unroll
    for (int off = 32; off; off >>= 1) mx = fmaxf(mx, __shfl_xor(mx, off));
    float ex = (t < 40) ? expf(v - mx) : 0.0f;
    float sum = ex;
    #pragma unroll
    for (int off = 32; off; off >>= 1) sum += __shfl_xor(sum, off);
    float lse = mx + logf(sum);
    if (t < 40) out[g*40 + t] = prow[t] - lse;
  }
}

extern "C" void kernel_launch(void* const* d_in, const int* in_sizes, int n_in,
                              void* d_out, int out_size, void* d_ws, size_t ws_size,
                              hipStream_t stream)
{
  const float* x    = (const float*)d_in[0];
  const int*   ei   = (const int*)d_in[1];
  const int*   batch= (const int*)d_in[2];
  const float* Wl   = (const float*)d_in[3];
  const float* bl   = (const float*)d_in[4];
  const float* Wr   = (const float*)d_in[5];
  const float* br   = (const float*)d_in[6];
  const float* gamma= (const float*)d_in[7];
  const float* beta = (const float*)d_in[8];
  const float* W1   = (const float*)d_in[9];
  const float* b1   = (const float*)d_in[10];
  const float* W2   = (const float*)d_in[11];
  const float* b2   = (const float*)d_in[12];
  float* out = (float*)d_out;

  const int N = in_sizes[0] / 128;
  const int E = in_sizes[1] / 2;
  const int G = out_size / 40;

  char* p = (char*)d_ws;
  auto carve = [&](size_t bytes)->char*{ char* r = p; p += alignup(bytes); return r; };
  float* mbuf     = (float*)carve((size_t)N * 128 * 4);
  float* hbuf     = (float*)carve((size_t)N * 128 * 4);
  float* zbuf     = (float*)carve((size_t)N * 40 * 4);
  int*   esrc     = (int*)carve((size_t)E * 4);
  int*   rs       = (int*)carve((size_t)N * 4);
  int*   cnt      = (int*)carve((size_t)N * 4);
  int*   cur      = (int*)carve((size_t)N * 4);
  int*   bsum     = (int*)carve(512 * 4);
  float* colstats = (float*)carve(256 * 4);
  float* bnp      = (float*)carve(256 * 4);
  float* Wc       = (float*)carve(40 * 128 * 4);
  float* bc       = (float*)carve(40 * 4);

  hipMemsetAsync(cnt, 0, (size_t)N * 4, stream);
  hipMemsetAsync(colstats, 0, 256 * 4, stream);

  const int eb = (E + 255) / 256;
  const int nb = (N + 255) / 256;   // 391 <= 512, handled by scan2
  count_kernel<<<eb, 256, 0, stream>>>(ei, E, cnt);
  scan1_kernel<<<nb, 256, 0, stream>>>(cnt, rs, bsum, N);
  scan2_kernel<<<1, 512, 0, stream>>>(bsum, nb);
  scan3_kernel<<<nb, 256, 0, stream>>>(rs, bsum, cur, N);
  fill_kernel<<<eb, 256, 0, stream>>>(ei, E, cur, esrc);
  wc_kernel<<<40, 128, 0, stream>>>(W1, b1, W2, b2, Wc, bc);

  const float Nf = (float)N;
  for (int l = 0; l < 3; ++l){
    const float* Ain = (l == 0) ? x : hbuf;
    gemm_dual<<<256, 512, 0, stream>>>(Ain, bnp, (l > 0) ? 1 : 0,
        Wr + (size_t)l * 16384, br + l * 128,
        Wl + (size_t)l * 16384, bl + l * 128,
        mbuf, hbuf, N);
    agg_kernel<<<1024, 256, 0, stream>>>(mbuf, rs, cnt, esrc, hbuf, colstats, N);
    bn_params_kernel<<<1, 128, 0, stream>>>(colstats, gamma + l * 128, beta + l * 128, bnp, Nf);
  }
  gemm_z<<<768, 512, 0, stream>>>(hbuf, bnp, Wc, bc, zbuf, N);
  pool_lsm_kernel<<<G, 256, 0, stream>>>(zbuf, batch, N, out);
}

// Round 2
// 613.870 us; speedup vs baseline: 1.7110x; 1.7110x over previous
//
#include <hip/hip_runtime.h>
#include <math.h>

// GraphSage GNN forward. N=100000 (div 32), E=600000, HID=128, OUT=40, G=64, L=3.
// R2: bf16 MFMA GEMMs (16x16x32), bf16 m/h buffers, shfl-broadcast unrolled gather agg.

typedef __bf16 bf16;
typedef __bf16 bf16x2 __attribute__((ext_vector_type(2)));
typedef __bf16 bf16x4 __attribute__((ext_vector_type(4)));
typedef __bf16 bf16x8 __attribute__((ext_vector_type(8)));
typedef float  f32x4  __attribute__((ext_vector_type(4)));

static inline size_t alignup(size_t x){ return (x + 255) & ~(size_t)255; }

__device__ inline float blo(unsigned u){ return __uint_as_float(u << 16); }
__device__ inline float bhi(unsigned u){ return __uint_as_float(u & 0xffff0000u); }

// ---------------- CSR build ----------------
__global__ void count_kernel(const int* __restrict__ ei, int E, int* __restrict__ cnt){
  int e = blockIdx.x*256 + threadIdx.x;
  if (e < E) atomicAdd(&cnt[ei[E + e]], 1);   // dst row
}

__global__ void scan1_kernel(const int* __restrict__ cnt, int* __restrict__ rs,
                             int* __restrict__ bsum, int N){
  __shared__ int s[256];
  int t = threadIdx.x;
  int i = blockIdx.x*256 + t;
  int v = (i < N) ? cnt[i] : 0;
  s[t] = v; __syncthreads();
  for (int off = 1; off < 256; off <<= 1){
    int x = (t >= off) ? s[t-off] : 0;
    __syncthreads();
    s[t] += x;
    __syncthreads();
  }
  if (i < N) rs[i] = s[t] - v;
  if (t == 255) bsum[blockIdx.x] = s[255];
}

__global__ void scan2_kernel(int* __restrict__ bsum, int NB){
  __shared__ int s[512];
  int t = threadIdx.x;
  int v = (t < NB) ? bsum[t] : 0;
  s[t] = v; __syncthreads();
  for (int off = 1; off < 512; off <<= 1){
    int x = (t >= off) ? s[t-off] : 0;
    __syncthreads();
    s[t] += x;
    __syncthreads();
  }
  if (t < NB) bsum[t] = s[t] - v;
}

__global__ void scan3_kernel(int* __restrict__ rs, const int* __restrict__ bsum,
                             int* __restrict__ cur, int N){
  int i = blockIdx.x*256 + threadIdx.x;
  if (i < N){
    int v = rs[i] + bsum[blockIdx.x];
    rs[i] = v;
    cur[i] = v;
  }
}

__global__ void fill_kernel(const int* __restrict__ ei, int E, int* __restrict__ cur,
                            int* __restrict__ esrc){
  int e = blockIdx.x*256 + threadIdx.x;
  if (e < E){
    int d = ei[E + e];
    int p = atomicAdd(&cur[d], 1);
    esrc[p] = ei[e];
  }
}

// ---------------- collapsed postMP weights: Wc = W2@W1 (40x128), bc = W2@b1 + b2 ----------------
__global__ void wc_kernel(const float* __restrict__ W1, const float* __restrict__ b1,
                          const float* __restrict__ W2, const float* __restrict__ b2,
                          float* __restrict__ Wc, float* __restrict__ bc){
  int o = blockIdx.x;        // 0..39
  int k = threadIdx.x;       // 0..127
  float s = 0.0f;
  for (int j = 0; j < 128; ++j) s = fmaf(W2[o*128 + j], W1[j*128 + k], s);
  Wc[o*128 + k] = s;
  __shared__ float r[128];
  r[k] = W2[o*128 + k] * b1[k];
  __syncthreads();
  for (int off = 64; off; off >>= 1){
    if (k < off) r[k] += r[k + off];
    __syncthreads();
  }
  if (k == 0) bc[o] = r[0] + b2[o];
}

// ---------------- weight bf16 prep: Wbf[l][r 0..255][k], rows 0..127 = Wr[l], 128..255 = Wl[l]
__global__ void wprep_kernel(const float* __restrict__ Wr, const float* __restrict__ Wl,
                             bf16* __restrict__ Wbf){
  int idx = blockIdx.x*256 + threadIdx.x;
  if (idx < 3*256*128){
    int l = idx / 32768, rem = idx % 32768, r = rem >> 7, k = rem & 127;
    float w = (r < 128) ? Wr[l*16384 + r*128 + k] : Wl[l*16384 + (r-128)*128 + k];
    Wbf[idx] = (bf16)w;
  }
}

__global__ void wcprep_kernel(const float* __restrict__ Wc, bf16* __restrict__ Wcbf){
  int idx = blockIdx.x*256 + threadIdx.x;   // 48*128
  if (idx < 48*128){
    int r = idx >> 7, k = idx & 127;
    Wcbf[idx] = (r < 40) ? (bf16)Wc[r*128 + k] : (bf16)0.0f;
  }
}

// ---------------- MFMA dual GEMM: Cm = act(A)@Wr^T + br (bf16), Ch = act(A)@Wl^T + bl (bf16)
// W staged once per block in LDS (rows 0..255 = [Wr;Wl], padded stride 136 bf16).
// mfma called as (W_frag, A_frag, acc): lane holds C[m = l16][n = quad*4+reg] -> packed bf16x4 stores.
__global__ __launch_bounds__(256, 2) void gemm_mfma_dual(
    const float* __restrict__ A32, const bf16* __restrict__ A16,
    const float* __restrict__ bnp, int layer0,
    const bf16* __restrict__ Wbf, const float* __restrict__ ba, const float* __restrict__ bb,
    bf16* __restrict__ Cm, bf16* __restrict__ Ch, int N)
{
  __shared__ bf16 wlds[256*136];   // 69632 B
  __shared__ bf16 alds[32*136];    // 8704 B
  const int t = threadIdx.x;

  for (int q = t; q < 256*16; q += 256){
    int row = q >> 4, seg = q & 15;
    bf16x8 v = *(const bf16x8*)(Wbf + row*128 + seg*8);
    *(bf16x8*)(wlds + row*136 + seg*8) = v;
  }

  const int wv = t >> 6, ln = t & 63;
  const int quad = ln >> 4, l16 = ln & 15;
  const int colbase = wv*64;

  // bias per (nt, reg): col = colbase + nt*16 + quad*4 + r  (hoisted out of tile loop)
  float biasv[4][4];
  #pragma unroll
  for (int nt = 0; nt < 4; ++nt)
    #pragma unroll
    for (int r = 0; r < 4; ++r){
      int c = colbase + nt*16 + quad*4 + r;
      biasv[nt][r] = (c < 128) ? ba[c] : bb[c - 128];
    }

  const int srow = t >> 3;          // staging row 0..31
  const int sc0  = (t & 7) * 16;    // staging col 0..112

  const int ntiles = N >> 5;
  for (int tile = blockIdx.x; tile < ntiles; tile += gridDim.x){
    const int rbase = tile << 5;
    __syncthreads();
    // ---- stage act(A) tile (32x128) to bf16 LDS ----
    {
      bf16* dst = alds + srow*136 + sc0;
      if (layer0){
        const float* src = A32 + (size_t)(rbase + srow)*128 + sc0;
        float4 v0 = *(const float4*)(src);
        float4 v1 = *(const float4*)(src + 4);
        float4 v2 = *(const float4*)(src + 8);
        float4 v3 = *(const float4*)(src + 12);
        bf16x8 o0, o1;
        o0[0]=(bf16)v0.x; o0[1]=(bf16)v0.y; o0[2]=(bf16)v0.z; o0[3]=(bf16)v0.w;
        o0[4]=(bf16)v1.x; o0[5]=(bf16)v1.y; o0[6]=(bf16)v1.z; o0[7]=(bf16)v1.w;
        o1[0]=(bf16)v2.x; o1[1]=(bf16)v2.y; o1[2]=(bf16)v2.z; o1[3]=(bf16)v2.w;
        o1[4]=(bf16)v3.x; o1[5]=(bf16)v3.y; o1[6]=(bf16)v3.z; o1[7]=(bf16)v3.w;
        *(bf16x8*)dst = o0; *(bf16x8*)(dst + 8) = o1;
      } else {
        const bf16* src = A16 + (size_t)(rbase + srow)*128 + sc0;
        bf16x8 i0 = *(const bf16x8*)(src);
        bf16x8 i1 = *(const bf16x8*)(src + 8);
        float sc[16], sh[16];
        *(float4*)(sc+0)  = *(const float4*)(bnp + sc0);
        *(float4*)(sc+4)  = *(const float4*)(bnp + sc0 + 4);
        *(float4*)(sc+8)  = *(const float4*)(bnp + sc0 + 8);
        *(float4*)(sc+12) = *(const float4*)(bnp + sc0 + 12);
        *(float4*)(sh+0)  = *(const float4*)(bnp + 128 + sc0);
        *(float4*)(sh+4)  = *(const float4*)(bnp + 128 + sc0 + 4);
        *(float4*)(sh+8)  = *(const float4*)(bnp + 128 + sc0 + 8);
        *(float4*)(sh+12) = *(const float4*)(bnp + 128 + sc0 + 12);
        bf16x8 o0, o1;
        #pragma unroll
        for (int j = 0; j < 8; ++j){
          float f0 = fmaxf(fmaf((float)i0[j], sc[j],     sh[j]),     0.0f);
          float f1 = fmaxf(fmaf((float)i1[j], sc[8 + j], sh[8 + j]), 0.0f);
          o0[j] = (bf16)f0; o1[j] = (bf16)f1;
        }
        *(bf16x8*)dst = o0; *(bf16x8*)(dst + 8) = o1;
      }
    }
    __syncthreads();
    // ---- MFMA: 2 m-tiles x 4 n-tiles per wave ----
    f32x4 acc[2][4];
    #pragma unroll
    for (int nt = 0; nt < 4; ++nt)
      #pragma unroll
      for (int r = 0; r < 4; ++r){
        acc[0][nt][r] = biasv[nt][r];
        acc[1][nt][r] = biasv[nt][r];
      }
    #pragma unroll
    for (int ks = 0; ks < 4; ++ks){
      const int ko = ks*32 + quad*8;
      bf16x8 af0 = *(const bf16x8*)(alds + l16*136 + ko);
      bf16x8 af1 = *(const bf16x8*)(alds + (16 + l16)*136 + ko);
      #pragma unroll
      for (int nt = 0; nt < 4; ++nt){
        bf16x8 wf = *(const bf16x8*)(wlds + (colbase + nt*16 + l16)*136 + ko);
        acc[0][nt] = __builtin_amdgcn_mfma_f32_16x16x32_bf16(wf, af0, acc[0][nt], 0, 0, 0);
        acc[1][nt] = __builtin_amdgcn_mfma_f32_16x16x32_bf16(wf, af1, acc[1][nt], 0, 0, 0);
      }
    }
    // ---- store: lane owns rows m = rbase + mt*16 + l16, cols n = colbase + nt*16 + quad*4 + 0..3
    bf16* op = (colbase < 128) ? Cm : Ch;
    const int cadj = (colbase < 128) ? 0 : 128;
    #pragma unroll
    for (int nt = 0; nt < 4; ++nt){
      int cc = colbase + nt*16 + quad*4 - cadj;
      #pragma unroll
      for (int mt = 0; mt < 2; ++mt){
        int row = rbase + mt*16 + l16;
        bf16x4 o;
        o[0] = (bf16)acc[mt][nt][0];
        o[1] = (bf16)acc[mt][nt][1];
        o[2] = (bf16)acc[mt][nt][2];
        o[3] = (bf16)acc[mt][nt][3];
        *(bf16x4*)(op + (size_t)row*128 + cc) = o;
      }
    }
  }
}

// ---------------- MFMA z GEMM: Z(fp32 Nx40) = act(A)@Wc^T + bc, cols padded to 48 ----------------
__global__ __launch_bounds__(256, 2) void gemm_mfma_z(
    const bf16* __restrict__ A16, const float* __restrict__ bnp,
    const bf16* __restrict__ Wcbf, const float* __restrict__ bc,
    float* __restrict__ Z, int N)
{
  __shared__ bf16 wlds[48*136];
  __shared__ bf16 alds[32*136];
  const int t = threadIdx.x;
  for (int q = t; q < 48*16; q += 256){
    int row = q >> 4, seg = q & 15;
    bf16x8 v = *(const bf16x8*)(Wcbf + row*128 + seg*8);
    *(bf16x8*)(wlds + row*136 + seg*8) = v;
  }
  const int wv = t >> 6, ln = t & 63;
  const int quad = ln >> 4, l16 = ln & 15;
  const int mycol = wv*16 + l16;                 // waves 0..2 cover cols 0..47
  const float bias = (wv < 3 && mycol < 40) ? bc[mycol] : 0.0f;
  const int srow = t >> 3;
  const int sc0  = (t & 7) * 16;

  const int ntiles = N >> 5;
  for (int tile = blockIdx.x; tile < ntiles; tile += gridDim.x){
    const int rbase = tile << 5;
    __syncthreads();
    {
      bf16* dst = alds + srow*136 + sc0;
      const bf16* src = A16 + (size_t)(rbase + srow)*128 + sc0;
      bf16x8 i0 = *(const bf16x8*)(src);
      bf16x8 i1 = *(const bf16x8*)(src + 8);
      float sc[16], sh[16];
      *(float4*)(sc+0)  = *(const float4*)(bnp + sc0);
      *(float4*)(sc+4)  = *(const float4*)(bnp + sc0 + 4);
      *(float4*)(sc+8)  = *(const float4*)(bnp + sc0 + 8);
      *(float4*)(sc+12) = *(const float4*)(bnp + sc0 + 12);
      *(float4*)(sh+0)  = *(const float4*)(bnp + 128 + sc0);
      *(float4*)(sh+4)  = *(const float4*)(bnp + 128 + sc0 + 4);
      *(float4*)(sh+8)  = *(const float4*)(bnp + 128 + sc0 + 8);
      *(float4*)(sh+12) = *(const float4*)(bnp + 128 + sc0 + 12);
      bf16x8 o0, o1;
      #pragma unroll
      for (int j = 0; j < 8; ++j){
        float f0 = fmaxf(fmaf((float)i0[j], sc[j],     sh[j]),     0.0f);
        float f1 = fmaxf(fmaf((float)i1[j], sc[8 + j], sh[8 + j]), 0.0f);
        o0[j] = (bf16)f0; o1[j] = (bf16)f1;
      }
      *(bf16x8*)dst = o0; *(bf16x8*)(dst + 8) = o1;
    }
    __syncthreads();
    if (wv < 3){
      f32x4 acc0 = {bias, bias, bias, bias};
      f32x4 acc1 = {bias, bias, bias, bias};
      #pragma unroll
      for (int ks = 0; ks < 4; ++ks){
        const int ko = ks*32 + quad*8;
        bf16x8 af0 = *(const bf16x8*)(alds + l16*136 + ko);
        bf16x8 af1 = *(const bf16x8*)(alds + (16 + l16)*136 + ko);
        bf16x8 wf  = *(const bf16x8*)(wlds + mycol*136 + ko);
        acc0 = __builtin_amdgcn_mfma_f32_16x16x32_bf16(af0, wf, acc0, 0, 0, 0);
        acc1 = __builtin_amdgcn_mfma_f32_16x16x32_bf16(af1, wf, acc1, 0, 0, 0);
      }
      if (mycol < 40){
        #pragma unroll
        for (int r = 0; r < 4; ++r){
          Z[(size_t)(rbase + quad*4 + r)*40 + mycol]      = acc0[r];
          Z[(size_t)(rbase + 16 + quad*4 + r)*40 + mycol] = acc1[r];
        }
      }
    }
  }
}

// ---------------- aggregation: h2 = hWl + gather-mean(m) ; L2-normalize ; BN stats (bf16 m/h)
__global__ __launch_bounds__(256) void agg_kernel(
    const bf16* __restrict__ m, const int* __restrict__ rs, const int* __restrict__ cnt,
    const int* __restrict__ esrc, bf16* __restrict__ h, float* __restrict__ colstats, int N)
{
  __shared__ float redS[4][128];
  __shared__ float redQ[4][128];
  const int t = threadIdx.x;
  const int w = t >> 6, lane = t & 63;
  float s0 = 0.f, s1 = 0.f, q0 = 0.f, q1 = 0.f;
  for (int n = blockIdx.x*4 + w; n < N; n += gridDim.x*4){
    int start = rs[n];
    int c = cnt[n];
    float ax = 0.f, ay = 0.f;
    int done = 0;
    while (done < c){
      int cc = min(c - done, 64);
      int my = (lane < cc) ? esrc[start + done + lane] : 0;  // lane-parallel src preload
      int e = 0;
      for (; e + 4 <= cc; e += 4){
        int sa = __shfl(my, e),   sb = __shfl(my, e+1);
        int sc = __shfl(my, e+2), sd = __shfl(my, e+3);
        unsigned ua = *(const unsigned*)(m + (size_t)sa*128 + lane*2);
        unsigned ub = *(const unsigned*)(m + (size_t)sb*128 + lane*2);
        unsigned uc = *(const unsigned*)(m + (size_t)sc*128 + lane*2);
        unsigned ud = *(const unsigned*)(m + (size_t)sd*128 + lane*2);
        ax += blo(ua) + blo(ub) + blo(uc) + blo(ud);
        ay += bhi(ua) + bhi(ub) + bhi(uc) + bhi(ud);
      }
      for (; e < cc; ++e){
        int sa = __shfl(my, e);
        unsigned ua = *(const unsigned*)(m + (size_t)sa*128 + lane*2);
        ax += blo(ua); ay += bhi(ua);
      }
      done += cc;
    }
    float inv = 1.0f / (float)max(c, 1);
    unsigned uh = *(const unsigned*)(h + (size_t)n*128 + lane*2);
    float x = fmaf(ax, inv, blo(uh));
    float y = fmaf(ay, inv, bhi(uh));
    float ss = x*x + y*y;
    #pragma unroll
    for (int off = 32; off; off >>= 1) ss += __shfl_xor(ss, off);
    float scale = 1.0f / fmaxf(sqrtf(ss), 1e-12f);
    x *= scale; y *= scale;
    bf16x2 o; o[0] = (bf16)x; o[1] = (bf16)y;
    *(bf16x2*)(h + (size_t)n*128 + lane*2) = o;
    s0 += x; s1 += y; q0 += x*x; q1 += y*y;
  }
  redS[w][lane*2]   = s0; redS[w][lane*2+1] = s1;
  redQ[w][lane*2]   = q0; redQ[w][lane*2+1] = q1;
  __syncthreads();
  if (t < 128){
    float S = redS[0][t] + redS[1][t] + redS[2][t] + redS[3][t];
    float Q = redQ[0][t] + redQ[1][t] + redQ[2][t] + redQ[3][t];
    atomicAdd(&colstats[t], S);
    atomicAdd(&colstats[128 + t], Q);
  }
}

// ---------------- BN params for next kernel's fused act; zero stats for next layer ----------------
__global__ void bn_params_kernel(float* __restrict__ cs, const float* __restrict__ gamma,
                                 const float* __restrict__ beta, float* __restrict__ bnp, float Nf){
  int t = threadIdx.x;   // 0..127
  float sum = cs[t], sq = cs[128 + t];
  float mu  = sum / Nf;
  float var = fmaxf(sq / Nf - mu*mu, 0.0f);
  float inv = rsqrtf(var + 1e-5f);
  float scale = gamma[t] * inv;
  bnp[t] = scale;
  bnp[128 + t] = beta[t] - mu * scale;
  cs[t] = 0.0f; cs[128 + t] = 0.0f;
}

// ---------------- pooled log-softmax, one block per graph (batch sorted) ----------------
__global__ void pool_lsm_kernel(const float* __restrict__ z, const int* __restrict__ batch,
                                int N, float* __restrict__ out)
{
  __shared__ int lohi[2];
  __shared__ float part[6][40];
  __shared__ float prow[40];
  const int g = blockIdx.x;
  const int t = threadIdx.x;
  if (t == 0){
    int lo = 0, hi = N;
    while (lo < hi){ int mid = (lo + hi) >> 1; if (batch[mid] < g) lo = mid + 1; else hi = mid; }
    lohi[0] = lo;
    int lo2 = lo, hi2 = N;
    while (lo2 < hi2){ int mid = (lo2 + hi2) >> 1; if (batch[mid] < g + 1) lo2 = mid + 1; else hi2 = mid; }
    lohi[1] = lo2;
  }
  __syncthreads();
  const int lo = lohi[0], hi = lohi[1];
  if (t < 240){
    int c = t % 40, nl = t / 40;
    float acc = 0.f;
    for (int n = lo + nl; n < hi; n += 6) acc += z[(size_t)n*40 + c];
    part[nl][c] = acc;
  }
  __syncthreads();
  if (t < 40) prow[t] = part[0][t] + part[1][t] + part[2][t] + part[3][t] + part[4][t] + part[5][t];
  __syncthreads();
  if (t < 64){
    float v = (t < 40) ? prow[t] : -3.0e38f;
    float mx = v;
    #pragma unroll
    for (int off = 32; off; off >>= 1) mx = fmaxf(mx, __shfl_xor(mx, off));
    float ex = (t < 40) ? expf(v - mx) : 0.0f;
    float sum = ex;
    #pragma unroll
    for (int off = 32; off; off >>= 1) sum += __shfl_xor(sum, off);
    float lse = mx + logf(sum);
    if (t < 40) out[g*40 + t] = prow[t] - lse;
  }
}

extern "C" void kernel_launch(void* const* d_in, const int* in_sizes, int n_in,
                              void* d_out, int out_size, void* d_ws, size_t ws_size,
                              hipStream_t stream)
{
  const float* x    = (const float*)d_in[0];
  const int*   ei   = (const int*)d_in[1];
  const int*   batch= (const int*)d_in[2];
  const float* Wl   = (const float*)d_in[3];
  const float* bl   = (const float*)d_in[4];
  const float* Wr   = (const float*)d_in[5];
  const float* br   = (const float*)d_in[6];
  const float* gamma= (const float*)d_in[7];
  const float* beta = (const float*)d_in[8];
  const float* W1   = (const float*)d_in[9];
  const float* b1   = (const float*)d_in[10];
  const float* W2   = (const float*)d_in[11];
  const float* b2   = (const float*)d_in[12];
  float* out = (float*)d_out;

  const int N = in_sizes[0] / 128;
  const int E = in_sizes[1] / 2;
  const int G = out_size / 40;

  char* p = (char*)d_ws;
  auto carve = [&](size_t bytes)->char*{ char* r = p; p += alignup(bytes); return r; };
  bf16*  mbuf     = (bf16*)carve((size_t)N * 128 * 2);
  bf16*  hbuf     = (bf16*)carve((size_t)N * 128 * 2);
  float* zbuf     = (float*)carve((size_t)N * 40 * 4);
  int*   esrc     = (int*)carve((size_t)E * 4);
  int*   rs       = (int*)carve((size_t)N * 4);
  int*   cnt      = (int*)carve((size_t)N * 4);
  int*   cur      = (int*)carve((size_t)N * 4);
  int*   bsum     = (int*)carve(512 * 4);
  float* colstats = (float*)carve(256 * 4);
  float* bnp      = (float*)carve(256 * 4);
  float* Wc       = (float*)carve(40 * 128 * 4);
  float* bc       = (float*)carve(40 * 4);
  bf16*  Wbf      = (bf16*)carve((size_t)3 * 256 * 128 * 2);
  bf16*  Wcbf     = (bf16*)carve((size_t)48 * 128 * 2);

  hipMemsetAsync(cnt, 0, (size_t)N * 4, stream);
  hipMemsetAsync(colstats, 0, 256 * 4, stream);

  const int eb = (E + 255) / 256;
  const int nb = (N + 255) / 256;   // 391 <= 512 (scan2 handles)
  count_kernel<<<eb, 256, 0, stream>>>(ei, E, cnt);
  scan1_kernel<<<nb, 256, 0, stream>>>(cnt, rs, bsum, N);
  scan2_kernel<<<1, 512, 0, stream>>>(bsum, nb);
  scan3_kernel<<<nb, 256, 0, stream>>>(rs, bsum, cur, N);
  fill_kernel<<<eb, 256, 0, stream>>>(ei, E, cur, esrc);
  wc_kernel<<<40, 128, 0, stream>>>(W1, b1, W2, b2, Wc, bc);
  wprep_kernel<<<(3*256*128 + 255)/256, 256, 0, stream>>>(Wr, Wl, Wbf);
  wcprep_kernel<<<(48*128 + 255)/256, 256, 0, stream>>>(Wc, Wcbf);

  const float Nf = (float)N;
  for (int l = 0; l < 3; ++l){
    gemm_mfma_dual<<<512, 256, 0, stream>>>(
        x, hbuf, bnp, (l == 0) ? 1 : 0,
        Wbf + (size_t)l * 32768, br + l * 128, bl + l * 128,
        mbuf, hbuf, N);
    agg_kernel<<<2048, 256, 0, stream>>>(mbuf, rs, cnt, esrc, hbuf, colstats, N);
    bn_params_kernel<<<1, 128, 0, stream>>>(colstats, gamma + l * 128, beta + l * 128, bnp, Nf);
  }
  gemm_mfma_z<<<512, 256, 0, stream>>>(hbuf, bnp, Wcbf, bc, zbuf, N);
  pool_lsm_kernel<<<G, 256, 0, stream>>>(zbuf, batch, N, out);
}

// Round 3
// 554.002 us; speedup vs baseline: 1.8959x; 1.1081x over previous
//
#include <hip/hip_runtime.h>
#include <math.h>

// GraphSage GNN forward. N=100000 (even, div 32), E=600000, HID=128, OUT=40, G=64, L=3.
// R3: commuted aggregation (gather h, not m) -> single K=256 GEMM per layer with
// fused L2-norm + BN-stats epilogue; W held in VGPRs; half-wave gather (2 nodes/wave).

typedef __bf16 bf16;
typedef __bf16 bf16x2 __attribute__((ext_vector_type(2)));
typedef __bf16 bf16x4 __attribute__((ext_vector_type(4)));
typedef __bf16 bf16x8 __attribute__((ext_vector_type(8)));
typedef float  f32x4  __attribute__((ext_vector_type(4)));

static inline size_t alignup(size_t x){ return (x + 255) & ~(size_t)255; }

__device__ inline float blo(unsigned u){ return __uint_as_float(u << 16); }
__device__ inline float bhi(unsigned u){ return __uint_as_float(u & 0xffff0000u); }

// ---------------- CSR build ----------------
__global__ void count_kernel(const int* __restrict__ ei, int E, int* __restrict__ cnt){
  int e = blockIdx.x*256 + threadIdx.x;
  if (e < E) atomicAdd(&cnt[ei[E + e]], 1);   // dst row
}

__global__ void scan1_kernel(const int* __restrict__ cnt, int* __restrict__ rs,
                             int* __restrict__ bsum, int N){
  __shared__ int s[256];
  int t = threadIdx.x;
  int i = blockIdx.x*256 + t;
  int v = (i < N) ? cnt[i] : 0;
  s[t] = v; __syncthreads();
  for (int off = 1; off < 256; off <<= 1){
    int x = (t >= off) ? s[t-off] : 0;
    __syncthreads();
    s[t] += x;
    __syncthreads();
  }
  if (i < N) rs[i] = s[t] - v;
  if (t == 255) bsum[blockIdx.x] = s[255];
}

__global__ void scan2_kernel(int* __restrict__ bsum, int NB){
  __shared__ int s[512];
  int t = threadIdx.x;
  int v = (t < NB) ? bsum[t] : 0;
  s[t] = v; __syncthreads();
  for (int off = 1; off < 512; off <<= 1){
    int x = (t >= off) ? s[t-off] : 0;
    __syncthreads();
    s[t] += x;
    __syncthreads();
  }
  if (t < NB) bsum[t] = s[t] - v;
}

__global__ void scan3_kernel(int* __restrict__ rs, const int* __restrict__ bsum,
                             int* __restrict__ cur, int N){
  int i = blockIdx.x*256 + threadIdx.x;
  if (i < N){
    int v = rs[i] + bsum[blockIdx.x];
    rs[i] = v;
    cur[i] = v;
  }
}

__global__ void fill_kernel(const int* __restrict__ ei, int E, int* __restrict__ cur,
                            int* __restrict__ esrc){
  int e = blockIdx.x*256 + threadIdx.x;
  if (e < E){
    int d = ei[E + e];
    int p = atomicAdd(&cur[d], 1);
    esrc[p] = ei[e];
  }
}

// ---------------- x -> bf16 ----------------
__global__ void xbf_kernel(const float* __restrict__ x, bf16* __restrict__ xb, int total8){
  int i = blockIdx.x*256 + threadIdx.x;
  if (i < total8){
    float4 a = *(const float4*)(x + (size_t)i*8);
    float4 b = *(const float4*)(x + (size_t)i*8 + 4);
    bf16x8 o;
    o[0]=(bf16)a.x; o[1]=(bf16)a.y; o[2]=(bf16)a.z; o[3]=(bf16)a.w;
    o[4]=(bf16)b.x; o[5]=(bf16)b.y; o[6]=(bf16)b.z; o[7]=(bf16)b.w;
    *(bf16x8*)(xb + (size_t)i*8) = o;
  }
}

// ---------------- collapsed postMP weights: Wc = W2@W1 (40x128), bc = W2@b1 + b2 ----------------
__global__ void wc_kernel(const float* __restrict__ W1, const float* __restrict__ b1,
                          const float* __restrict__ W2, const float* __restrict__ b2,
                          float* __restrict__ Wc, float* __restrict__ bc){
  int o = blockIdx.x;        // 0..39
  int k = threadIdx.x;       // 0..127
  float s = 0.0f;
  for (int j = 0; j < 128; ++j) s = fmaf(W2[o*128 + j], W1[j*128 + k], s);
  Wc[o*128 + k] = s;
  __shared__ float r[128];
  r[k] = W2[o*128 + k] * b1[k];
  __syncthreads();
  for (int off = 64; off; off >>= 1){
    if (k < off) r[k] += r[k + off];
    __syncthreads();
  }
  if (k == 0) bc[o] = r[0] + b2[o];
}

// ---------------- weight prep: Wbig[l][c][k], k<128 -> Wl[l][c][k], k>=128 -> Wr[l][c][k-128]
__global__ void wprep_kernel(const float* __restrict__ Wl, const float* __restrict__ Wr,
                             bf16* __restrict__ Wbig){
  int idx = blockIdx.x*256 + threadIdx.x;
  if (idx < 3*128*256){
    int l = idx / 32768, rem = idx % 32768, c = rem >> 8, k = rem & 255;
    float w = (k < 128) ? Wl[l*16384 + c*128 + k] : Wr[l*16384 + c*128 + (k-128)];
    Wbig[idx] = (bf16)w;
  }
}

__global__ void wcprep_kernel(const float* __restrict__ Wc, bf16* __restrict__ Wcbf){
  int idx = blockIdx.x*256 + threadIdx.x;   // 48*128
  if (idx < 48*128){
    int r = idx >> 7, k = idx & 127;
    Wcbf[idx] = (r < 40) ? (bf16)Wc[r*128 + k] : (bf16)0.0f;
  }
}

// ---------------- gather: aggx[n] = mean_{j in N(n)} act(h[j]); act = relu(sc*h+sh) if use_act
// half-wave design: 2 nodes per wave, 32 lanes x 8B per gathered row.
__global__ __launch_bounds__(256) void gather_kernel(
    const bf16* __restrict__ hsrc, const float* __restrict__ bnp, int use_act,
    const int* __restrict__ rs, const int* __restrict__ cnt, const int* __restrict__ esrc,
    bf16* __restrict__ aggx, int N)
{
  const int t = threadIdx.x;
  const int lane = t & 63;
  const int hw = lane >> 5;
  const int hl = lane & 31;
  const int wid = (blockIdx.x * 256 + t) >> 6;
  const int nw = (gridDim.x * 256) >> 6;
  float sc0=1.f, sc1=1.f, sc2=1.f, sc3=1.f, sh0=0.f, sh1=0.f, sh2=0.f, sh3=0.f;
  if (use_act){
    float4 s4 = *(const float4*)(bnp + hl*4);
    float4 h4 = *(const float4*)(bnp + 128 + hl*4);
    sc0=s4.x; sc1=s4.y; sc2=s4.z; sc3=s4.w;
    sh0=h4.x; sh1=h4.y; sh2=h4.z; sh3=h4.w;
  }
  const int npair = N >> 1;   // N even
  for (int p = wid; p < npair; p += nw){
    const int n = p*2 + hw;
    const int start = rs[n];
    const int c = cnt[n];
    float a0=0.f, a1=0.f, a2=0.f, a3=0.f;
    int done = 0;
    while (done < c){
      int cc = min(c - done, 32);
      int my = (hl < cc) ? esrc[start + done + hl] : 0;
      int e = 0;
      for (; e + 4 <= cc; e += 4){
        int i0 = __shfl(my, hw*32 + e);
        int i1 = __shfl(my, hw*32 + e + 1);
        int i2 = __shfl(my, hw*32 + e + 2);
        int i3 = __shfl(my, hw*32 + e + 3);
        uint2 u0 = *(const uint2*)(hsrc + (size_t)i0*128 + hl*4);
        uint2 u1 = *(const uint2*)(hsrc + (size_t)i1*128 + hl*4);
        uint2 u2 = *(const uint2*)(hsrc + (size_t)i2*128 + hl*4);
        uint2 u3 = *(const uint2*)(hsrc + (size_t)i3*128 + hl*4);
        if (use_act){
          a0 += fmaxf(fmaf(blo(u0.x), sc0, sh0), 0.f) + fmaxf(fmaf(blo(u1.x), sc0, sh0), 0.f)
              + fmaxf(fmaf(blo(u2.x), sc0, sh0), 0.f) + fmaxf(fmaf(blo(u3.x), sc0, sh0), 0.f);
          a1 += fmaxf(fmaf(bhi(u0.x), sc1, sh1), 0.f) + fmaxf(fmaf(bhi(u1.x), sc1, sh1), 0.f)
              + fmaxf(fmaf(bhi(u2.x), sc1, sh1), 0.f) + fmaxf(fmaf(bhi(u3.x), sc1, sh1), 0.f);
          a2 += fmaxf(fmaf(blo(u0.y), sc2, sh2), 0.f) + fmaxf(fmaf(blo(u1.y), sc2, sh2), 0.f)
              + fmaxf(fmaf(blo(u2.y), sc2, sh2), 0.f) + fmaxf(fmaf(blo(u3.y), sc2, sh2), 0.f);
          a3 += fmaxf(fmaf(bhi(u0.y), sc3, sh3), 0.f) + fmaxf(fmaf(bhi(u1.y), sc3, sh3), 0.f)
              + fmaxf(fmaf(bhi(u2.y), sc3, sh3), 0.f) + fmaxf(fmaf(bhi(u3.y), sc3, sh3), 0.f);
        } else {
          a0 += blo(u0.x) + blo(u1.x) + blo(u2.x) + blo(u3.x);
          a1 += bhi(u0.x) + bhi(u1.x) + bhi(u2.x) + bhi(u3.x);
          a2 += blo(u0.y) + blo(u1.y) + blo(u2.y) + blo(u3.y);
          a3 += bhi(u0.y) + bhi(u1.y) + bhi(u2.y) + bhi(u3.y);
        }
      }
      for (; e < cc; ++e){
        int i0 = __shfl(my, hw*32 + e);
        uint2 u0 = *(const uint2*)(hsrc + (size_t)i0*128 + hl*4);
        if (use_act){
          a0 += fmaxf(fmaf(blo(u0.x), sc0, sh0), 0.f);
          a1 += fmaxf(fmaf(bhi(u0.x), sc1, sh1), 0.f);
          a2 += fmaxf(fmaf(blo(u0.y), sc2, sh2), 0.f);
          a3 += fmaxf(fmaf(bhi(u0.y), sc3, sh3), 0.f);
        } else {
          a0 += blo(u0.x); a1 += bhi(u0.x); a2 += blo(u0.y); a3 += bhi(u0.y);
        }
      }
      done += cc;
    }
    float inv = 1.0f / (float)max(c, 1);
    bf16x4 o;
    o[0] = (bf16)(a0*inv); o[1] = (bf16)(a1*inv);
    o[2] = (bf16)(a2*inv); o[3] = (bf16)(a3*inv);
    *(bf16x4*)(aggx + (size_t)n*128 + hl*4) = o;
  }
}

// ---------------- fused GEMM K=256: h2 = [act(h)|aggx] @ [Wl;Wr]^T + bl + br (br dropped for deg-0),
// then per-row L2-normalize, store bf16, accumulate BN column stats.
// Block 256 = 4 waves (col groups of 32), tile 32 rows x 128 cols. W in VGPRs.
__global__ __launch_bounds__(256, 3) void gemm_fused(
    const bf16* __restrict__ hin, const bf16* __restrict__ aggx,
    const float* __restrict__ bnp, int use_act,
    const bf16* __restrict__ Wbig, const float* __restrict__ bl, const float* __restrict__ br,
    const int* __restrict__ cnt, bf16* __restrict__ hout, float* __restrict__ colstats, int N)
{
  __shared__ bf16 alds[32*256];    // 16 KB, XOR-swizzled 16B chunks
  __shared__ float rowsq[32];
  __shared__ float colsum[128];
  __shared__ float colsq[128];
  const int t = threadIdx.x;
  const int wv = t >> 6, lane = t & 63;
  const int quad = lane >> 4, l16 = lane & 15;
  const int cbase = wv * 32;

  // W fragments in registers: wreg[nt][ks] = W[col = cbase+nt*16+l16][k = ks*32+quad*8 ..+7]
  bf16x8 wreg[2][8];
  #pragma unroll
  for (int nt = 0; nt < 2; ++nt){
    const bf16* wp = Wbig + (size_t)(cbase + nt*16 + l16) * 256 + quad*8;
    #pragma unroll
    for (int ks = 0; ks < 8; ++ks)
      wreg[nt][ks] = *(const bf16x8*)(wp + ks*32);
  }
  // bias per acc lane-col: col = cbase + nt*16 + quad*4 + r
  float biasv[2][4], brv[2][4];
  #pragma unroll
  for (int nt = 0; nt < 2; ++nt){
    int c0 = cbase + nt*16 + quad*4;
    float4 b4 = *(const float4*)(bl + c0);
    float4 r4 = *(const float4*)(br + c0);
    biasv[nt][0] = b4.x + r4.x; biasv[nt][1] = b4.y + r4.y;
    biasv[nt][2] = b4.z + r4.z; biasv[nt][3] = b4.w + r4.w;
    brv[nt][0] = r4.x; brv[nt][1] = r4.y; brv[nt][2] = r4.z; brv[nt][3] = r4.w;
  }
  if (t < 128){ colsum[t] = 0.f; colsq[t] = 0.f; }

  const int srow = t >> 3, seg = t & 7;
  const int ntiles = (N + 31) >> 5;
  for (int tile = blockIdx.x; tile < ntiles; tile += gridDim.x){
    const int rbase = tile << 5;
    __syncthreads();
    if (t < 32) rowsq[t] = 0.f;
    // ---- stage A = [act(h) | aggx] (32 x 256) ----
    {
      const int grow = rbase + srow;
      const bool vld = grow < N;
      #pragma unroll
      for (int j = 0; j < 4; ++j){
        const int chunk = seg*4 + j;
        const int col = seg*32 + j*8;
        bf16x8 v;
        #pragma unroll
        for (int q = 0; q < 8; ++q) v[q] = (bf16)0.0f;
        if (vld){
          if (col < 128){
            v = *(const bf16x8*)(hin + (size_t)grow*128 + col);
            if (use_act){
              float4 s0 = *(const float4*)(bnp + col);
              float4 s1 = *(const float4*)(bnp + col + 4);
              float4 h0 = *(const float4*)(bnp + 128 + col);
              float4 h1 = *(const float4*)(bnp + 128 + col + 4);
              float scv[8] = {s0.x,s0.y,s0.z,s0.w,s1.x,s1.y,s1.z,s1.w};
              float shv[8] = {h0.x,h0.y,h0.z,h0.w,h1.x,h1.y,h1.z,h1.w};
              #pragma unroll
              for (int q = 0; q < 8; ++q)
                v[q] = (bf16)fmaxf(fmaf((float)v[q], scv[q], shv[q]), 0.0f);
            }
          } else {
            v = *(const bf16x8*)(aggx + (size_t)grow*128 + (col - 128));
          }
        }
        *(bf16x8*)(alds + srow*256 + ((chunk ^ (srow & 7)) * 8)) = v;
      }
    }
    __syncthreads();
    // ---- MFMA K-loop ----
    f32x4 acc[2][2];
    #pragma unroll
    for (int mt = 0; mt < 2; ++mt)
      #pragma unroll
      for (int nt = 0; nt < 2; ++nt)
        #pragma unroll
        for (int r = 0; r < 4; ++r) acc[mt][nt][r] = biasv[nt][r];
    #pragma unroll
    for (int ks = 0; ks < 8; ++ks){
      const int ch = ((ks*4 + quad) ^ (l16 & 7)) * 8;
      bf16x8 af0 = *(const bf16x8*)(alds + l16*256 + ch);
      bf16x8 af1 = *(const bf16x8*)(alds + (l16 + 16)*256 + ch);
      acc[0][0] = __builtin_amdgcn_mfma_f32_16x16x32_bf16(wreg[0][ks], af0, acc[0][0], 0, 0, 0);
      acc[0][1] = __builtin_amdgcn_mfma_f32_16x16x32_bf16(wreg[1][ks], af0, acc[0][1], 0, 0, 0);
      acc[1][0] = __builtin_amdgcn_mfma_f32_16x16x32_bf16(wreg[0][ks], af1, acc[1][0], 0, 0, 0);
      acc[1][1] = __builtin_amdgcn_mfma_f32_16x16x32_bf16(wreg[1][ks], af1, acc[1][1], 0, 0, 0);
    }
    // ---- epilogue: deg-0 bias fix, row L2-norm, store, BN stats ----
    const int grow0 = rbase + l16;
    const int grow1 = grow0 + 16;
    const bool v0 = grow0 < N, v1 = grow1 < N;
    const int c0 = v0 ? cnt[grow0] : 1;
    const int c1 = v1 ? cnt[grow1] : 1;
    if (c0 == 0){
      #pragma unroll
      for (int nt = 0; nt < 2; ++nt)
        #pragma unroll
        for (int r = 0; r < 4; ++r) acc[0][nt][r] -= brv[nt][r];
    }
    if (c1 == 0){
      #pragma unroll
      for (int nt = 0; nt < 2; ++nt)
        #pragma unroll
        for (int r = 0; r < 4; ++r) acc[1][nt][r] -= brv[nt][r];
    }
    float s0 = 0.f, s1 = 0.f;
    #pragma unroll
    for (int nt = 0; nt < 2; ++nt)
      #pragma unroll
      for (int r = 0; r < 4; ++r){
        s0 += acc[0][nt][r] * acc[0][nt][r];
        s1 += acc[1][nt][r] * acc[1][nt][r];
      }
    s0 += __shfl_xor(s0, 16); s0 += __shfl_xor(s0, 32);
    s1 += __shfl_xor(s1, 16); s1 += __shfl_xor(s1, 32);
    if (quad == 0){
      atomicAdd(&rowsq[l16], s0);
      atomicAdd(&rowsq[l16 + 16], s1);
    }
    __syncthreads();
    const float scl0 = 1.0f / fmaxf(sqrtf(rowsq[l16]), 1e-12f);
    const float scl1 = 1.0f / fmaxf(sqrtf(rowsq[l16 + 16]), 1e-12f);
    float cs[2][4], cq[2][4];
    #pragma unroll
    for (int nt = 0; nt < 2; ++nt){
      const int col = cbase + nt*16 + quad*4;
      bf16x4 o0, o1;
      #pragma unroll
      for (int r = 0; r < 4; ++r){
        float x0 = acc[0][nt][r] * scl0;
        float x1 = acc[1][nt][r] * scl1;
        o0[r] = (bf16)x0; o1[r] = (bf16)x1;
        float m0 = v0 ? x0 : 0.f;
        float m1 = v1 ? x1 : 0.f;
        cs[nt][r] = m0 + m1;
        cq[nt][r] = m0*m0 + m1*m1;
      }
      if (v0) *(bf16x4*)(hout + (size_t)grow0*128 + col) = o0;
      if (v1) *(bf16x4*)(hout + (size_t)grow1*128 + col) = o1;
    }
    #pragma unroll
    for (int nt = 0; nt < 2; ++nt)
      #pragma unroll
      for (int r = 0; r < 4; ++r){
        float a = cs[nt][r], b = cq[nt][r];
        #pragma unroll
        for (int off = 1; off < 16; off <<= 1){
          a += __shfl_xor(a, off);
          b += __shfl_xor(b, off);
        }
        cs[nt][r] = a; cq[nt][r] = b;
      }
    if (l16 == 0){
      #pragma unroll
      for (int nt = 0; nt < 2; ++nt){
        const int col = cbase + nt*16 + quad*4;
        #pragma unroll
        for (int r = 0; r < 4; ++r){
          atomicAdd(&colsum[col + r], cs[nt][r]);
          atomicAdd(&colsq[col + r], cq[nt][r]);
        }
      }
    }
  }
  __syncthreads();
  if (t < 128){
    atomicAdd(&colstats[t], colsum[t]);
    atomicAdd(&colstats[128 + t], colsq[t]);
  }
}

// ---------------- MFMA z GEMM: Z(fp32 Nx40) = act(A)@Wc^T + bc ----------------
__global__ __launch_bounds__(256, 2) void gemm_mfma_z(
    const bf16* __restrict__ A16, const float* __restrict__ bnp,
    const bf16* __restrict__ Wcbf, const float* __restrict__ bc,
    float* __restrict__ Z, int N)
{
  __shared__ bf16 wlds[48*136];
  __shared__ bf16 alds[32*136];
  const int t = threadIdx.x;
  for (int q = t; q < 48*16; q += 256){
    int row = q >> 4, seg = q & 15;
    bf16x8 v = *(const bf16x8*)(Wcbf + row*128 + seg*8);
    *(bf16x8*)(wlds + row*136 + seg*8) = v;
  }
  const int wv = t >> 6, ln = t & 63;
  const int quad = ln >> 4, l16 = ln & 15;
  const int mycol = wv*16 + l16;
  const float bias = (wv < 3 && mycol < 40) ? bc[mycol] : 0.0f;
  const int srow = t >> 3;
  const int sc0  = (t & 7) * 16;

  const int ntiles = N >> 5;
  for (int tile = blockIdx.x; tile < ntiles; tile += gridDim.x){
    const int rbase = tile << 5;
    __syncthreads();
    {
      bf16* dst = alds + srow*136 + sc0;
      const bf16* src = A16 + (size_t)(rbase + srow)*128 + sc0;
      bf16x8 i0 = *(const bf16x8*)(src);
      bf16x8 i1 = *(const bf16x8*)(src + 8);
      float sc[16], sh[16];
      *(float4*)(sc+0)  = *(const float4*)(bnp + sc0);
      *(float4*)(sc+4)  = *(const float4*)(bnp + sc0 + 4);
      *(float4*)(sc+8)  = *(const float4*)(bnp + sc0 + 8);
      *(float4*)(sc+12) = *(const float4*)(bnp + sc0 + 12);
      *(float4*)(sh+0)  = *(const float4*)(bnp + 128 + sc0);
      *(float4*)(sh+4)  = *(const float4*)(bnp + 128 + sc0 + 4);
      *(float4*)(sh+8)  = *(const float4*)(bnp + 128 + sc0 + 8);
      *(float4*)(sh+12) = *(const float4*)(bnp + 128 + sc0 + 12);
      bf16x8 o0, o1;
      #pragma unroll
      for (int j = 0; j < 8; ++j){
        float f0 = fmaxf(fmaf((float)i0[j], sc[j],     sh[j]),     0.0f);
        float f1 = fmaxf(fmaf((float)i1[j], sc[8 + j], sh[8 + j]), 0.0f);
        o0[j] = (bf16)f0; o1[j] = (bf16)f1;
      }
      *(bf16x8*)dst = o0; *(bf16x8*)(dst + 8) = o1;
    }
    __syncthreads();
    if (wv < 3){
      f32x4 acc0 = {bias, bias, bias, bias};
      f32x4 acc1 = {bias, bias, bias, bias};
      #pragma unroll
      for (int ks = 0; ks < 4; ++ks){
        const int ko = ks*32 + quad*8;
        bf16x8 af0 = *(const bf16x8*)(alds + l16*136 + ko);
        bf16x8 af1 = *(const bf16x8*)(alds + (16 + l16)*136 + ko);
        bf16x8 wf  = *(const bf16x8*)(wlds + mycol*136 + ko);
        acc0 = __builtin_amdgcn_mfma_f32_16x16x32_bf16(af0, wf, acc0, 0, 0, 0);
        acc1 = __builtin_amdgcn_mfma_f32_16x16x32_bf16(af1, wf, acc1, 0, 0, 0);
      }
      if (mycol < 40){
        #pragma unroll
        for (int r = 0; r < 4; ++r){
          Z[(size_t)(rbase + quad*4 + r)*40 + mycol]      = acc0[r];
          Z[(size_t)(rbase + 16 + quad*4 + r)*40 + mycol] = acc1[r];
        }
      }
    }
  }
}

// ---------------- BN params; zero stats for next layer ----------------
__global__ void bn_params_kernel(float* __restrict__ cs, const float* __restrict__ gamma,
                                 const float* __restrict__ beta, float* __restrict__ bnp, float Nf){
  int t = threadIdx.x;   // 0..127
  float sum = cs[t], sq = cs[128 + t];
  float mu  = sum / Nf;
  float var = fmaxf(sq / Nf - mu*mu, 0.0f);
  float inv = rsqrtf(var + 1e-5f);
  float scale = gamma[t] * inv;
  bnp[t] = scale;
  bnp[128 + t] = beta[t] - mu * scale;
  cs[t] = 0.0f; cs[128 + t] = 0.0f;
}

// ---------------- pooled log-softmax, one block per graph (batch sorted) ----------------
__global__ void pool_lsm_kernel(const float* __restrict__ z, const int* __restrict__ batch,
                                int N, float* __restrict__ out)
{
  __shared__ int lohi[2];
  __shared__ float part[6][40];
  __shared__ float prow[40];
  const int g = blockIdx.x;
  const int t = threadIdx.x;
  if (t == 0){
    int lo = 0, hi = N;
    while (lo < hi){ int mid = (lo + hi) >> 1; if (batch[mid] < g) lo = mid + 1; else hi = mid; }
    lohi[0] = lo;
    int lo2 = lo, hi2 = N;
    while (lo2 < hi2){ int mid = (lo2 + hi2) >> 1; if (batch[mid] < g + 1) lo2 = mid + 1; else hi2 = mid; }
    lohi[1] = lo2;
  }
  __syncthreads();
  const int lo = lohi[0], hi = lohi[1];
  if (t < 240){
    int c = t % 40, nl = t / 40;
    float acc = 0.f;
    for (int n = lo + nl; n < hi; n += 6) acc += z[(size_t)n*40 + c];
    part[nl][c] = acc;
  }
  __syncthreads();
  if (t < 40) prow[t] = part[0][t] + part[1][t] + part[2][t] + part[3][t] + part[4][t] + part[5][t];
  __syncthreads();
  if (t < 64){
    float v = (t < 40) ? prow[t] : -3.0e38f;
    float mx = v;
    #pragma unroll
    for (int off = 32; off; off >>= 1) mx = fmaxf(mx, __shfl_xor(mx, off));
    float ex = (t < 40) ? expf(v - mx) : 0.0f;
    float sum = ex;
    #pragma unroll
    for (int off = 32; off; off >>= 1) sum += __shfl_xor(sum, off);
    float lse = mx + logf(sum);
    if (t < 40) out[g*40 + t] = prow[t] - lse;
  }
}

extern "C" void kernel_launch(void* const* d_in, const int* in_sizes, int n_in,
                              void* d_out, int out_size, void* d_ws, size_t ws_size,
                              hipStream_t stream)
{
  const float* x    = (const float*)d_in[0];
  const int*   ei   = (const int*)d_in[1];
  const int*   batch= (const int*)d_in[2];
  const float* Wl   = (const float*)d_in[3];
  const float* bl   = (const float*)d_in[4];
  const float* Wr   = (const float*)d_in[5];
  const float* br   = (const float*)d_in[6];
  const float* gamma= (const float*)d_in[7];
  const float* beta = (const float*)d_in[8];
  const float* W1   = (const float*)d_in[9];
  const float* b1   = (const float*)d_in[10];
  const float* W2   = (const float*)d_in[11];
  const float* b2   = (const float*)d_in[12];
  float* out = (float*)d_out;

  const int N = in_sizes[0] / 128;
  const int E = in_sizes[1] / 2;
  const int G = out_size / 40;

  char* p = (char*)d_ws;
  auto carve = [&](size_t bytes)->char*{ char* r = p; p += alignup(bytes); return r; };
  bf16*  xbf      = (bf16*)carve((size_t)N * 128 * 2);
  bf16*  aggx     = (bf16*)carve((size_t)N * 128 * 2);
  bf16*  hbuf     = (bf16*)carve((size_t)N * 128 * 2);
  float* zbuf     = (float*)carve((size_t)N * 40 * 4);
  int*   esrc     = (int*)carve((size_t)E * 4);
  int*   rs       = (int*)carve((size_t)N * 4);
  int*   cnt      = (int*)carve((size_t)N * 4);
  int*   cur      = (int*)carve((size_t)N * 4);
  int*   bsum     = (int*)carve(512 * 4);
  float* colstats = (float*)carve(256 * 4);
  float* bnp      = (float*)carve(256 * 4);
  float* Wc       = (float*)carve(40 * 128 * 4);
  float* bc       = (float*)carve(40 * 4);
  bf16*  Wbig     = (bf16*)carve((size_t)3 * 128 * 256 * 2);
  bf16*  Wcbf     = (bf16*)carve((size_t)48 * 128 * 2);

  hipMemsetAsync(cnt, 0, (size_t)N * 4, stream);
  hipMemsetAsync(colstats, 0, 256 * 4, stream);

  const int eb = (E + 255) / 256;
  const int nb = (N + 255) / 256;
  count_kernel<<<eb, 256, 0, stream>>>(ei, E, cnt);
  scan1_kernel<<<nb, 256, 0, stream>>>(cnt, rs, bsum, N);
  scan2_kernel<<<1, 512, 0, stream>>>(bsum, nb);
  scan3_kernel<<<nb, 256, 0, stream>>>(rs, bsum, cur, N);
  fill_kernel<<<eb, 256, 0, stream>>>(ei, E, cur, esrc);
  xbf_kernel<<<(N*16 + 255)/256, 256, 0, stream>>>(x, xbf, N*16);
  wc_kernel<<<40, 128, 0, stream>>>(W1, b1, W2, b2, Wc, bc);
  wprep_kernel<<<(3*128*256 + 255)/256, 256, 0, stream>>>(Wl, Wr, Wbig);
  wcprep_kernel<<<(48*128 + 255)/256, 256, 0, stream>>>(Wc, Wcbf);

  const float Nf = (float)N;
  for (int l = 0; l < 3; ++l){
    const bf16* hin = (l == 0) ? xbf : hbuf;
    gather_kernel<<<4096, 256, 0, stream>>>(hin, bnp, (l > 0) ? 1 : 0,
                                            rs, cnt, esrc, aggx, N);
    gemm_fused<<<1024, 256, 0, stream>>>(hin, aggx, bnp, (l > 0) ? 1 : 0,
                                         Wbig + (size_t)l * 32768, bl + l*128, br + l*128,
                                         cnt, hbuf, colstats, N);
    bn_params_kernel<<<1, 128, 0, stream>>>(colstats, gamma + l*128, beta + l*128, bnp, Nf);
  }
  gemm_mfma_z<<<512, 256, 0, stream>>>(hbuf, bnp, Wcbf, bc, zbuf, N);
  pool_lsm_kernel<<<G, 256, 0, stream>>>(zbuf, batch, N, out);
}

// Round 4
// 495.111 us; speedup vs baseline: 2.1215x; 1.1189x over previous
//
#include <hip/hip_runtime.h>
#include <math.h>

// GraphSage GNN forward. N=100000 (div 32), E=600000, HID=128, OUT=40, G=64, L=3.
// R4: pooling commuted past the output GEMM (pool act(h) -> tiny 64x128x40 GEMM);
// gather reshaped to 4 nodes/wave with 16B row loads.

typedef __bf16 bf16;
typedef __bf16 bf16x2 __attribute__((ext_vector_type(2)));
typedef __bf16 bf16x4 __attribute__((ext_vector_type(4)));
typedef __bf16 bf16x8 __attribute__((ext_vector_type(8)));
typedef float  f32x4  __attribute__((ext_vector_type(4)));

static inline size_t alignup(size_t x){ return (x + 255) & ~(size_t)255; }

__device__ inline float blo(unsigned u){ return __uint_as_float(u << 16); }
__device__ inline float bhi(unsigned u){ return __uint_as_float(u & 0xffff0000u); }

// ---------------- CSR build ----------------
__global__ void count_kernel(const int* __restrict__ ei, int E, int* __restrict__ cnt){
  int e = blockIdx.x*256 + threadIdx.x;
  if (e < E) atomicAdd(&cnt[ei[E + e]], 1);   // dst row
}

__global__ void scan1_kernel(const int* __restrict__ cnt, int* __restrict__ rs,
                             int* __restrict__ bsum, int N){
  __shared__ int s[256];
  int t = threadIdx.x;
  int i = blockIdx.x*256 + t;
  int v = (i < N) ? cnt[i] : 0;
  s[t] = v; __syncthreads();
  for (int off = 1; off < 256; off <<= 1){
    int x = (t >= off) ? s[t-off] : 0;
    __syncthreads();
    s[t] += x;
    __syncthreads();
  }
  if (i < N) rs[i] = s[t] - v;
  if (t == 255) bsum[blockIdx.x] = s[255];
}

__global__ void scan2_kernel(int* __restrict__ bsum, int NB){
  __shared__ int s[512];
  int t = threadIdx.x;
  int v = (t < NB) ? bsum[t] : 0;
  s[t] = v; __syncthreads();
  for (int off = 1; off < 512; off <<= 1){
    int x = (t >= off) ? s[t-off] : 0;
    __syncthreads();
    s[t] += x;
    __syncthreads();
  }
  if (t < NB) bsum[t] = s[t] - v;
}

__global__ void scan3_kernel(int* __restrict__ rs, const int* __restrict__ bsum,
                             int* __restrict__ cur, int N){
  int i = blockIdx.x*256 + threadIdx.x;
  if (i < N){
    int v = rs[i] + bsum[blockIdx.x];
    rs[i] = v;
    cur[i] = v;
  }
}

__global__ void fill_kernel(const int* __restrict__ ei, int E, int* __restrict__ cur,
                            int* __restrict__ esrc){
  int e = blockIdx.x*256 + threadIdx.x;
  if (e < E){
    int d = ei[E + e];
    int p = atomicAdd(&cur[d], 1);
    esrc[p] = ei[e];
  }
}

// ---------------- x -> bf16 ----------------
__global__ void xbf_kernel(const float* __restrict__ x, bf16* __restrict__ xb, int total8){
  int i = blockIdx.x*256 + threadIdx.x;
  if (i < total8){
    float4 a = *(const float4*)(x + (size_t)i*8);
    float4 b = *(const float4*)(x + (size_t)i*8 + 4);
    bf16x8 o;
    o[0]=(bf16)a.x; o[1]=(bf16)a.y; o[2]=(bf16)a.z; o[3]=(bf16)a.w;
    o[4]=(bf16)b.x; o[5]=(bf16)b.y; o[6]=(bf16)b.z; o[7]=(bf16)b.w;
    *(bf16x8*)(xb + (size_t)i*8) = o;
  }
}

// ---------------- collapsed postMP weights: Wc = W2@W1 (40x128), bc = W2@b1 + b2 ----------------
__global__ void wc_kernel(const float* __restrict__ W1, const float* __restrict__ b1,
                          const float* __restrict__ W2, const float* __restrict__ b2,
                          float* __restrict__ Wc, float* __restrict__ bc){
  int o = blockIdx.x;        // 0..39
  int k = threadIdx.x;       // 0..127
  float s = 0.0f;
  for (int j = 0; j < 128; ++j) s = fmaf(W2[o*128 + j], W1[j*128 + k], s);
  Wc[o*128 + k] = s;
  __shared__ float r[128];
  r[k] = W2[o*128 + k] * b1[k];
  __syncthreads();
  for (int off = 64; off; off >>= 1){
    if (k < off) r[k] += r[k + off];
    __syncthreads();
  }
  if (k == 0) bc[o] = r[0] + b2[o];
}

// ---------------- weight prep: Wbig[l][c][k], k<128 -> Wl[l][c][k], k>=128 -> Wr[l][c][k-128]
__global__ void wprep_kernel(const float* __restrict__ Wl, const float* __restrict__ Wr,
                             bf16* __restrict__ Wbig){
  int idx = blockIdx.x*256 + threadIdx.x;
  if (idx < 3*128*256){
    int l = idx / 32768, rem = idx % 32768, c = rem >> 8, k = rem & 255;
    float w = (k < 128) ? Wl[l*16384 + c*128 + k] : Wr[l*16384 + c*128 + (k-128)];
    Wbig[idx] = (bf16)w;
  }
}

// ---------------- gather: aggx[n] = mean_{j in N(n)} act(h[j]); act = relu(sc*h+sh) if use_act
// 4 nodes per wave, 16 lanes x 16B (bf16x8) per gathered row.
__global__ __launch_bounds__(256) void gather_kernel(
    const bf16* __restrict__ hsrc, const float* __restrict__ bnp, int use_act,
    const int* __restrict__ rs, const int* __restrict__ cnt, const int* __restrict__ esrc,
    bf16* __restrict__ aggx, int N)
{
  const int t = threadIdx.x;
  const int lane = t & 63;
  const int q  = lane >> 4;    // node slot 0..3 in wave
  const int ql = lane & 15;    // 16B segment owner within row
  const int wid = (blockIdx.x * 256 + t) >> 6;
  const int nw = (gridDim.x * 256) >> 6;
  float sc[8], sh[8];
  if (use_act){
    *(float4*)(sc)   = *(const float4*)(bnp + ql*8);
    *(float4*)(sc+4) = *(const float4*)(bnp + ql*8 + 4);
    *(float4*)(sh)   = *(const float4*)(bnp + 128 + ql*8);
    *(float4*)(sh+4) = *(const float4*)(bnp + 128 + ql*8 + 4);
  }
  const int ngrp = N >> 2;   // N divisible by 4
  for (int p = wid; p < ngrp; p += nw){
    const int n = p*4 + q;
    const int start = rs[n];
    const int c = cnt[n];
    float a[8];
    #pragma unroll
    for (int j = 0; j < 8; ++j) a[j] = 0.f;
    int done = 0;
    while (done < c){
      int cc = min(c - done, 16);
      int my = (ql < cc) ? esrc[start + done + ql] : 0;
      int e = 0;
      for (; e + 4 <= cc; e += 4){
        int i0 = __shfl(my, q*16 + e);
        int i1 = __shfl(my, q*16 + e + 1);
        int i2 = __shfl(my, q*16 + e + 2);
        int i3 = __shfl(my, q*16 + e + 3);
        bf16x8 v0 = *(const bf16x8*)(hsrc + (size_t)i0*128 + ql*8);
        bf16x8 v1 = *(const bf16x8*)(hsrc + (size_t)i1*128 + ql*8);
        bf16x8 v2 = *(const bf16x8*)(hsrc + (size_t)i2*128 + ql*8);
        bf16x8 v3 = *(const bf16x8*)(hsrc + (size_t)i3*128 + ql*8);
        if (use_act){
          #pragma unroll
          for (int j = 0; j < 8; ++j){
            a[j] += fmaxf(fmaf((float)v0[j], sc[j], sh[j]), 0.f)
                  + fmaxf(fmaf((float)v1[j], sc[j], sh[j]), 0.f)
                  + fmaxf(fmaf((float)v2[j], sc[j], sh[j]), 0.f)
                  + fmaxf(fmaf((float)v3[j], sc[j], sh[j]), 0.f);
          }
        } else {
          #pragma unroll
          for (int j = 0; j < 8; ++j)
            a[j] += (float)v0[j] + (float)v1[j] + (float)v2[j] + (float)v3[j];
        }
      }
      for (; e < cc; ++e){
        int i0 = __shfl(my, q*16 + e);
        bf16x8 v0 = *(const bf16x8*)(hsrc + (size_t)i0*128 + ql*8);
        if (use_act){
          #pragma unroll
          for (int j = 0; j < 8; ++j)
            a[j] += fmaxf(fmaf((float)v0[j], sc[j], sh[j]), 0.f);
        } else {
          #pragma unroll
          for (int j = 0; j < 8; ++j) a[j] += (float)v0[j];
        }
      }
      done += cc;
    }
    float inv = 1.0f / (float)max(c, 1);
    bf16x8 o;
    #pragma unroll
    for (int j = 0; j < 8; ++j) o[j] = (bf16)(a[j] * inv);
    *(bf16x8*)(aggx + (size_t)n*128 + ql*8) = o;
  }
}

// ---------------- fused GEMM K=256: h2 = [act(h)|aggx] @ [Wl;Wr]^T + bl + br (br dropped deg-0),
// then per-row L2-normalize, store bf16, accumulate BN column stats. W in VGPRs.
__global__ __launch_bounds__(256, 3) void gemm_fused(
    const bf16* __restrict__ hin, const bf16* __restrict__ aggx,
    const float* __restrict__ bnp, int use_act,
    const bf16* __restrict__ Wbig, const float* __restrict__ bl, const float* __restrict__ br,
    const int* __restrict__ cnt, bf16* __restrict__ hout, float* __restrict__ colstats, int N)
{
  __shared__ bf16 alds[32*256];    // 16 KB, XOR-swizzled 16B chunks
  __shared__ float rowsq[32];
  __shared__ float colsum[128];
  __shared__ float colsq[128];
  const int t = threadIdx.x;
  const int wv = t >> 6, lane = t & 63;
  const int quad = lane >> 4, l16 = lane & 15;
  const int cbase = wv * 32;

  bf16x8 wreg[2][8];
  #pragma unroll
  for (int nt = 0; nt < 2; ++nt){
    const bf16* wp = Wbig + (size_t)(cbase + nt*16 + l16) * 256 + quad*8;
    #pragma unroll
    for (int ks = 0; ks < 8; ++ks)
      wreg[nt][ks] = *(const bf16x8*)(wp + ks*32);
  }
  float biasv[2][4], brv[2][4];
  #pragma unroll
  for (int nt = 0; nt < 2; ++nt){
    int c0 = cbase + nt*16 + quad*4;
    float4 b4 = *(const float4*)(bl + c0);
    float4 r4 = *(const float4*)(br + c0);
    biasv[nt][0] = b4.x + r4.x; biasv[nt][1] = b4.y + r4.y;
    biasv[nt][2] = b4.z + r4.z; biasv[nt][3] = b4.w + r4.w;
    brv[nt][0] = r4.x; brv[nt][1] = r4.y; brv[nt][2] = r4.z; brv[nt][3] = r4.w;
  }
  if (t < 128){ colsum[t] = 0.f; colsq[t] = 0.f; }

  const int srow = t >> 3, seg = t & 7;
  const int ntiles = (N + 31) >> 5;
  for (int tile = blockIdx.x; tile < ntiles; tile += gridDim.x){
    const int rbase = tile << 5;
    __syncthreads();
    if (t < 32) rowsq[t] = 0.f;
    {
      const int grow = rbase + srow;
      const bool vld = grow < N;
      #pragma unroll
      for (int j = 0; j < 4; ++j){
        const int chunk = seg*4 + j;
        const int col = seg*32 + j*8;
        bf16x8 v;
        #pragma unroll
        for (int qq = 0; qq < 8; ++qq) v[qq] = (bf16)0.0f;
        if (vld){
          if (col < 128){
            v = *(const bf16x8*)(hin + (size_t)grow*128 + col);
            if (use_act){
              float4 s0 = *(const float4*)(bnp + col);
              float4 s1 = *(const float4*)(bnp + col + 4);
              float4 h0 = *(const float4*)(bnp + 128 + col);
              float4 h1 = *(const float4*)(bnp + 128 + col + 4);
              float scv[8] = {s0.x,s0.y,s0.z,s0.w,s1.x,s1.y,s1.z,s1.w};
              float shv[8] = {h0.x,h0.y,h0.z,h0.w,h1.x,h1.y,h1.z,h1.w};
              #pragma unroll
              for (int qq = 0; qq < 8; ++qq)
                v[qq] = (bf16)fmaxf(fmaf((float)v[qq], scv[qq], shv[qq]), 0.0f);
            }
          } else {
            v = *(const bf16x8*)(aggx + (size_t)grow*128 + (col - 128));
          }
        }
        *(bf16x8*)(alds + srow*256 + ((chunk ^ (srow & 7)) * 8)) = v;
      }
    }
    __syncthreads();
    f32x4 acc[2][2];
    #pragma unroll
    for (int mt = 0; mt < 2; ++mt)
      #pragma unroll
      for (int nt = 0; nt < 2; ++nt)
        #pragma unroll
        for (int r = 0; r < 4; ++r) acc[mt][nt][r] = biasv[nt][r];
    #pragma unroll
    for (int ks = 0; ks < 8; ++ks){
      const int ch = ((ks*4 + quad) ^ (l16 & 7)) * 8;
      bf16x8 af0 = *(const bf16x8*)(alds + l16*256 + ch);
      bf16x8 af1 = *(const bf16x8*)(alds + (l16 + 16)*256 + ch);
      acc[0][0] = __builtin_amdgcn_mfma_f32_16x16x32_bf16(wreg[0][ks], af0, acc[0][0], 0, 0, 0);
      acc[0][1] = __builtin_amdgcn_mfma_f32_16x16x32_bf16(wreg[1][ks], af0, acc[0][1], 0, 0, 0);
      acc[1][0] = __builtin_amdgcn_mfma_f32_16x16x32_bf16(wreg[0][ks], af1, acc[1][0], 0, 0, 0);
      acc[1][1] = __builtin_amdgcn_mfma_f32_16x16x32_bf16(wreg[1][ks], af1, acc[1][1], 0, 0, 0);
    }
    const int grow0 = rbase + l16;
    const int grow1 = grow0 + 16;
    const bool v0 = grow0 < N, v1 = grow1 < N;
    const int c0 = v0 ? cnt[grow0] : 1;
    const int c1 = v1 ? cnt[grow1] : 1;
    if (c0 == 0){
      #pragma unroll
      for (int nt = 0; nt < 2; ++nt)
        #pragma unroll
        for (int r = 0; r < 4; ++r) acc[0][nt][r] -= brv[nt][r];
    }
    if (c1 == 0){
      #pragma unroll
      for (int nt = 0; nt < 2; ++nt)
        #pragma unroll
        for (int r = 0; r < 4; ++r) acc[1][nt][r] -= brv[nt][r];
    }
    float s0 = 0.f, s1 = 0.f;
    #pragma unroll
    for (int nt = 0; nt < 2; ++nt)
      #pragma unroll
      for (int r = 0; r < 4; ++r){
        s0 += acc[0][nt][r] * acc[0][nt][r];
        s1 += acc[1][nt][r] * acc[1][nt][r];
      }
    s0 += __shfl_xor(s0, 16); s0 += __shfl_xor(s0, 32);
    s1 += __shfl_xor(s1, 16); s1 += __shfl_xor(s1, 32);
    if (quad == 0){
      atomicAdd(&rowsq[l16], s0);
      atomicAdd(&rowsq[l16 + 16], s1);
    }
    __syncthreads();
    const float scl0 = 1.0f / fmaxf(sqrtf(rowsq[l16]), 1e-12f);
    const float scl1 = 1.0f / fmaxf(sqrtf(rowsq[l16 + 16]), 1e-12f);
    float cs[2][4], cq[2][4];
    #pragma unroll
    for (int nt = 0; nt < 2; ++nt){
      const int col = cbase + nt*16 + quad*4;
      bf16x4 o0, o1;
      #pragma unroll
      for (int r = 0; r < 4; ++r){
        float x0 = acc[0][nt][r] * scl0;
        float x1 = acc[1][nt][r] * scl1;
        o0[r] = (bf16)x0; o1[r] = (bf16)x1;
        float m0 = v0 ? x0 : 0.f;
        float m1 = v1 ? x1 : 0.f;
        cs[nt][r] = m0 + m1;
        cq[nt][r] = m0*m0 + m1*m1;
      }
      if (v0) *(bf16x4*)(hout + (size_t)grow0*128 + col) = o0;
      if (v1) *(bf16x4*)(hout + (size_t)grow1*128 + col) = o1;
    }
    #pragma unroll
    for (int nt = 0; nt < 2; ++nt)
      #pragma unroll
      for (int r = 0; r < 4; ++r){
        float a = cs[nt][r], b = cq[nt][r];
        #pragma unroll
        for (int off = 1; off < 16; off <<= 1){
          a += __shfl_xor(a, off);
          b += __shfl_xor(b, off);
        }
        cs[nt][r] = a; cq[nt][r] = b;
      }
    if (l16 == 0){
      #pragma unroll
      for (int nt = 0; nt < 2; ++nt){
        const int col = cbase + nt*16 + quad*4;
        #pragma unroll
        for (int r = 0; r < 4; ++r){
          atomicAdd(&colsum[col + r], cs[nt][r]);
          atomicAdd(&colsq[col + r], cq[nt][r]);
        }
      }
    }
  }
  __syncthreads();
  if (t < 128){
    atomicAdd(&colstats[t], colsum[t]);
    atomicAdd(&colstats[128 + t], colsq[t]);
  }
}

// ---------------- BN params; zero stats for next layer ----------------
__global__ void bn_params_kernel(float* __restrict__ cs, const float* __restrict__ gamma,
                                 const float* __restrict__ beta, float* __restrict__ bnp, float Nf){
  int t = threadIdx.x;   // 0..127
  float sum = cs[t], sq = cs[128 + t];
  float mu  = sum / Nf;
  float var = fmaxf(sq / Nf - mu*mu, 0.0f);
  float inv = rsqrtf(var + 1e-5f);
  float scale = gamma[t] * inv;
  bnp[t] = scale;
  bnp[128 + t] = beta[t] - mu * scale;
  cs[t] = 0.0f; cs[128 + t] = 0.0f;
}

// ---------------- pool act(h) per graph: pooledh[g][k] = sum_{n in g} relu(sc*h+sh) ----------------
__global__ __launch_bounds__(256) void poolh_kernel(
    const bf16* __restrict__ h, const float* __restrict__ bnp,
    const int* __restrict__ batch, float* __restrict__ pooledh, int N)
{
  const int t = threadIdx.x;
  const int col = t & 127;
  const int half = t >> 7;
  const float sc = bnp[col];
  const float sh = bnp[128 + col];
  const int chunk = (N + gridDim.x - 1) / gridDim.x;
  const int lo = blockIdx.x * chunk;
  const int hi = min(N, lo + chunk);
  if (lo >= hi) return;
  int gcur = -1;
  float acc = 0.f;
  for (int n = lo + half; n < hi; n += 2){
    int g = batch[n];
    if (g != gcur){
      if (gcur >= 0) atomicAdd(&pooledh[gcur*128 + col], acc);
      gcur = g; acc = 0.f;
    }
    float v = (float)h[(size_t)n*128 + col];
    acc += fmaxf(fmaf(v, sc, sh), 0.f);
  }
  if (gcur >= 0) atomicAdd(&pooledh[gcur*128 + col], acc);
}

// ---------------- final: out[g] = log_softmax(pooledh[g] @ Wc^T + cnt_g*bc) ----------------
__global__ void lsm_kernel(const float* __restrict__ ph, const float* __restrict__ Wc,
                           const float* __restrict__ bc, const int* __restrict__ batch,
                           int N, float* __restrict__ out)
{
  __shared__ int cntg_s;
  const int g = blockIdx.x;
  const int t = threadIdx.x;   // 64 threads = one wave
  if (t == 0){
    int lo = 0, hi = N;
    while (lo < hi){ int mid = (lo + hi) >> 1; if (batch[mid] < g) lo = mid + 1; else hi = mid; }
    int lo2 = lo, hi2 = N;
    while (lo2 < hi2){ int mid = (lo2 + hi2) >> 1; if (batch[mid] < g + 1) lo2 = mid + 1; else hi2 = mid; }
    cntg_s = lo2 - lo;
  }
  __syncthreads();
  float z = -3.0e38f;
  if (t < 40){
    float s = (float)cntg_s * bc[t];
    const float* phg = ph + g*128;
    const float* w = Wc + t*128;
    for (int k = 0; k < 128; k += 4){
      float4 a = *(const float4*)(phg + k);
      float4 b = *(const float4*)(w + k);
      s = fmaf(a.x, b.x, s); s = fmaf(a.y, b.y, s);
      s = fmaf(a.z, b.z, s); s = fmaf(a.w, b.w, s);
    }
    z = s;
  }
  float mx = z;
  #pragma unroll
  for (int off = 32; off; off >>= 1) mx = fmaxf(mx, __shfl_xor(mx, off));
  float ex = (t < 40) ? expf(z - mx) : 0.0f;
  float sum = ex;
  #pragma unroll
  for (int off = 32; off; off >>= 1) sum += __shfl_xor(sum, off);
  float lse = mx + logf(sum);
  if (t < 40) out[g*40 + t] = z - lse;
}

extern "C" void kernel_launch(void* const* d_in, const int* in_sizes, int n_in,
                              void* d_out, int out_size, void* d_ws, size_t ws_size,
                              hipStream_t stream)
{
  const float* x    = (const float*)d_in[0];
  const int*   ei   = (const int*)d_in[1];
  const int*   batch= (const int*)d_in[2];
  const float* Wl   = (const float*)d_in[3];
  const float* bl   = (const float*)d_in[4];
  const float* Wr   = (const float*)d_in[5];
  const float* br   = (const float*)d_in[6];
  const float* gamma= (const float*)d_in[7];
  const float* beta = (const float*)d_in[8];
  const float* W1   = (const float*)d_in[9];
  const float* b1   = (const float*)d_in[10];
  const float* W2   = (const float*)d_in[11];
  const float* b2   = (const float*)d_in[12];
  float* out = (float*)d_out;

  const int N = in_sizes[0] / 128;
  const int E = in_sizes[1] / 2;
  const int G = out_size / 40;

  char* p = (char*)d_ws;
  auto carve = [&](size_t bytes)->char*{ char* r = p; p += alignup(bytes); return r; };
  bf16*  xbf      = (bf16*)carve((size_t)N * 128 * 2);
  bf16*  aggx     = (bf16*)carve((size_t)N * 128 * 2);
  bf16*  hbuf     = (bf16*)carve((size_t)N * 128 * 2);
  int*   esrc     = (int*)carve((size_t)E * 4);
  int*   rs       = (int*)carve((size_t)N * 4);
  int*   cnt      = (int*)carve((size_t)N * 4);
  int*   cur      = (int*)carve((size_t)N * 4);
  int*   bsum     = (int*)carve(512 * 4);
  float* colstats = (float*)carve(256 * 4);
  float* bnp      = (float*)carve(256 * 4);
  float* Wc       = (float*)carve(40 * 128 * 4);
  float* bc       = (float*)carve(40 * 4);
  bf16*  Wbig     = (bf16*)carve((size_t)3 * 128 * 256 * 2);
  float* pooledh  = (float*)carve((size_t)G * 128 * 4);

  hipMemsetAsync(cnt, 0, (size_t)N * 4, stream);
  hipMemsetAsync(colstats, 0, 256 * 4, stream);
  hipMemsetAsync(pooledh, 0, (size_t)G * 128 * 4, stream);

  const int eb = (E + 255) / 256;
  const int nb = (N + 255) / 256;
  count_kernel<<<eb, 256, 0, stream>>>(ei, E, cnt);
  scan1_kernel<<<nb, 256, 0, stream>>>(cnt, rs, bsum, N);
  scan2_kernel<<<1, 512, 0, stream>>>(bsum, nb);
  scan3_kernel<<<nb, 256, 0, stream>>>(rs, bsum, cur, N);
  fill_kernel<<<eb, 256, 0, stream>>>(ei, E, cur, esrc);
  xbf_kernel<<<(N*16 + 255)/256, 256, 0, stream>>>(x, xbf, N*16);
  wc_kernel<<<40, 128, 0, stream>>>(W1, b1, W2, b2, Wc, bc);
  wprep_kernel<<<(3*128*256 + 255)/256, 256, 0, stream>>>(Wl, Wr, Wbig);

  const float Nf = (float)N;
  for (int l = 0; l < 3; ++l){
    const bf16* hin = (l == 0) ? xbf : hbuf;
    gather_kernel<<<4096, 256, 0, stream>>>(hin, bnp, (l > 0) ? 1 : 0,
                                            rs, cnt, esrc, aggx, N);
    gemm_fused<<<1024, 256, 0, stream>>>(hin, aggx, bnp, (l > 0) ? 1 : 0,
                                         Wbig + (size_t)l * 32768, bl + l*128, br + l*128,
                                         cnt, hbuf, colstats, N);
    bn_params_kernel<<<1, 128, 0, stream>>>(colstats, gamma + l*128, beta + l*128, bnp, Nf);
  }
  poolh_kernel<<<1024, 256, 0, stream>>>(hbuf, bnp, batch, pooledh, N);
  lsm_kernel<<<G, 64, 0, stream>>>(pooledh, Wc, bc, batch, N, out);
}